// Round 1
// baseline (9.736 us; speedup 1.0000x reference)
//
#include <hip/hip_runtime.h>
#include <hip/hip_bf16.h>

// Embedding gather: out[b,s,:] = table[x[b,s], :]
// x: [4,2048] int32 (8192 tokens), table: [32000,128] f32, out: [8192,128] f32.
// One float4 (16B) per thread; 32 threads per token row (128 f32 = 32 float4).

__global__ __launch_bounds__(256) void embedding_gather_kernel(
    const int* __restrict__ x,
    const float4* __restrict__ table,   // [32000][32] float4
    float4* __restrict__ out,           // [8192][32] float4
    int n_tokens)
{
    int gid = blockIdx.x * blockDim.x + threadIdx.x;   // one float4 per thread
    int token = gid >> 5;          // gid / 32
    int elem  = gid & 31;          // gid % 32
    if (token < n_tokens) {
        int row = x[token];
        out[(size_t)token * 32 + elem] = table[(size_t)row * 32 + elem];
    }
}

extern "C" void kernel_launch(void* const* d_in, const int* in_sizes, int n_in,
                              void* d_out, int out_size, void* d_ws, size_t ws_size,
                              hipStream_t stream) {
    const int*    x     = (const int*)d_in[0];
    const float4* table = (const float4*)d_in[1];
    float4*       out   = (float4*)d_out;

    const int n_tokens = in_sizes[0];            // 8192
    const int total    = n_tokens * 32;          // float4 units
    const int block    = 256;
    const int grid     = (total + block - 1) / block;   // 1024

    embedding_gather_kernel<<<grid, block, 0, stream>>>(x, table, out, n_tokens);
}